// Round 1
// baseline (2889.790 us; speedup 1.0000x reference)
//
#include <hip/hip_runtime.h>
#include <cstdint>

#define TC 18
#define HW 180
#define EPSF 1e-5f

// ws layout (float offsets)
#define N_SHARED (2*HW*HW*64)              // 4,147,200  NHWC shared buffer
#define OFF_WTS   (N_SHARED)
#define N_WTS     (512*9*64)               // 294,912   [ic][k][oc]
#define OFF_WMT   (OFF_WTS + N_WTS)
#define N_WMT     (36*64*9*64)             // 1,327,104 [g][ic][k][oc]
#define OFF_W2T   (OFF_WMT + N_WMT)
#define N_W2T     (36*64*9*3)              // 62,208    [g][ic][k][o]

__global__ __launch_bounds__(256) void prep_kernel(
    const float* __restrict__ w_s, const float* __restrict__ w_hm1,
    const float* __restrict__ w_attr1, const float* __restrict__ w_hm2,
    const float* __restrict__ w_attr2, float* __restrict__ ws) {
  int idx = blockIdx.x * 256 + threadIdx.x;
  if (idx < N_WTS) {
    int oc = idx & 63;
    int k  = (idx >> 6) % 9;
    int ic = idx / 576;
    ws[OFF_WTS + idx] = w_s[(oc*512 + ic)*9 + k];
    return;
  }
  idx -= N_WTS;
  if (idx < N_WMT) {
    int oc = idx & 63;
    int k  = (idx >> 6) % 9;
    int ic = (idx / 576) & 63;
    int g  = idx / 36864;
    float v;
    if (g < 6) v = w_hm1[((g*64 + oc)*64 + ic)*9 + k];
    else       v = w_attr1[(((g-6)*64 + oc)*64 + ic)*9 + k];
    ws[OFF_WMT + idx] = v;
    return;
  }
  idx -= N_WMT;
  if (idx < N_W2T) {
    int o  = idx % 3;
    int k  = (idx/3) % 9;
    int ic = (idx/27) & 63;
    int g  = idx / 1728;
    float v = 0.f;
    if (g < 6) { if (o < 2) v = w_hm2[((g*2 + o)*64 + ic)*9 + k]; }
    else       v = w_attr2[(((g-6)*3 + o)*64 + ic)*9 + k];
    ws[OFF_W2T + idx] = v;
  }
}

// Kernel A: shared conv 512->64 per tile, BN+ReLU, masked. Output NHWC.
__global__ __launch_bounds__(256) void shared_conv_kernel(
    const float* __restrict__ x, const int* __restrict__ tmask,
    const float* __restrict__ wTs,
    const float* __restrict__ g_s, const float* __restrict__ b_s,
    const float* __restrict__ m_s, const float* __restrict__ v_s,
    float* __restrict__ shbuf) {
  int bid = blockIdx.x;
  int b = bid / (TC*TC);
  int t = bid % (TC*TC);
  int ty = t / TC, tx = t % TC;
  int Y0 = ty*10, X0 = tx*10;
  int tid = threadIdx.x;
  int oc = tid & 63, pg = tid >> 6;
  int prb = (pg >> 1)*5, pcb = (pg & 1)*5;
  float* shp = shbuf + (size_t)b*HW*HW*64;
  bool active = tmask[b*TC*TC + t] != 0;
  if (!active) {
    #pragma unroll
    for (int r = 0; r < 5; r++)
      #pragma unroll
      for (int c = 0; c < 5; c++) {
        int gy = Y0 + prb + r, gx = X0 + pcb + c;
        shp[((size_t)gy*HW + gx)*64 + oc] = 0.f;
      }
    return;
  }
  __shared__ float xl[64][144];   // [ic chunk][12x12 px]
  float acc[25];
  #pragma unroll
  for (int i = 0; i < 25; i++) acc[i] = 0.f;

  for (int ch = 0; ch < 512; ch += 64) {
    __syncthreads();
    for (int idx = tid; idx < 64*144; idx += 256) {
      int px = idx % 144;
      int c  = idx / 144;
      int ry = px / 12, rx = px % 12;
      int gy = Y0 - 1 + ry, gx = X0 - 1 + rx;
      float v = 0.f;
      if (gy >= 0 && gy < HW && gx >= 0 && gx < HW &&
          tmask[b*TC*TC + (gy/10)*TC + (gx/10)] != 0)
        v = x[(((size_t)b*512 + (ch + c))*HW + gy)*HW + gx];
      xl[c][px] = v;
    }
    __syncthreads();
    #pragma unroll 1
    for (int c = 0; c < 64; c++) {
      float w[9];
      #pragma unroll
      for (int k = 0; k < 9; k++)
        w[k] = wTs[((ch + c)*9 + k)*64 + oc];
      float xr[49];
      #pragma unroll
      for (int r = 0; r < 7; r++)
        #pragma unroll
        for (int cc = 0; cc < 7; cc++)
          xr[r*7 + cc] = xl[c][(prb + r)*12 + (pcb + cc)];
      #pragma unroll
      for (int r = 0; r < 5; r++)
        #pragma unroll
        for (int cc = 0; cc < 5; cc++) {
          float a = acc[r*5 + cc];
          #pragma unroll
          for (int ky = 0; ky < 3; ky++)
            #pragma unroll
            for (int kx = 0; kx < 3; kx++)
              a = fmaf(xr[(r + ky)*7 + (cc + kx)], w[ky*3 + kx], a);
          acc[r*5 + cc] = a;
        }
    }
  }
  float sc  = g_s[oc] * rsqrtf(v_s[oc] + EPSF);
  float sht = b_s[oc] - m_s[oc]*sc;
  #pragma unroll
  for (int r = 0; r < 5; r++)
    #pragma unroll
    for (int c = 0; c < 5; c++) {
      int gy = Y0 + prb + r, gx = X0 + pcb + c;
      float v = fmaxf(acc[r*5 + c]*sc + sht, 0.f);
      shp[((size_t)gy*HW + gx)*64 + oc] = v;
    }
}

// Kernel B: per (tile, group): mid conv 64->64 (12x12, BN+ReLU+mask) into LDS,
// then grouped conv 64->{2,3} (10x10) + bias -> d_out.
__global__ __launch_bounds__(256) void branch_conv_kernel(
    const float* __restrict__ shbuf, const int* __restrict__ tmask,
    const float* __restrict__ wmT, const float* __restrict__ w2T,
    const float* __restrict__ g_h, const float* __restrict__ b_h,
    const float* __restrict__ m_h, const float* __restrict__ v_h,
    const float* __restrict__ g_a, const float* __restrict__ b_a,
    const float* __restrict__ m_a, const float* __restrict__ v_a,
    const float* __restrict__ bias_hm, const float* __restrict__ bias_attr,
    float* __restrict__ out) {
  int bid = blockIdx.x;
  int g = bid % 36;
  int t = bid / 36;
  int b = t / (TC*TC); t %= TC*TC;
  int ty = t / TC, tx = t % TC;
  int Y0 = ty*10, X0 = tx*10;
  int tid = threadIdx.x;
  int Oc = (g < 6) ? 2 : 3;
  int cobase = (g < 6) ? g*2 : 12 + (g - 6)*3;
  bool active = tmask[b*TC*TC + ty*TC + tx] != 0;
  if (!active) {
    if (tid < 100) {
      int py = tid / 10, pxx = tid % 10;
      for (int o = 0; o < Oc; o++)
        out[(((size_t)b*102 + cobase + o)*HW + (Y0 + py))*HW + (X0 + pxx)] = 0.f;
    }
    return;
  }
  __shared__ float sh[196][20];   // 14x14 px, 16-ch chunk (pad 20)
  __shared__ float h[144][68];    // 12x12 px, 64 ch (pad 68)
  int oc = tid & 63, pg = tid >> 6;
  int rb = (pg >> 1)*6, cb = (pg & 1)*6;
  float acc[36];
  #pragma unroll
  for (int i = 0; i < 36; i++) acc[i] = 0.f;

  for (int ch = 0; ch < 64; ch += 16) {
    __syncthreads();
    for (int idx = tid; idx < 196*16; idx += 256) {
      int c  = idx & 15;
      int px = idx >> 4;
      int ry = px / 14, rx = px % 14;
      int gy = Y0 - 2 + ry, gx = X0 - 2 + rx;
      float v = 0.f;
      if (gy >= 0 && gy < HW && gx >= 0 && gx < HW)
        v = shbuf[(((size_t)b*HW + gy)*HW + gx)*64 + ch + c];
      sh[px][c] = v;
    }
    __syncthreads();
    #pragma unroll 1
    for (int c = 0; c < 16; c++) {
      int ic = ch + c;
      float w[9];
      #pragma unroll
      for (int k = 0; k < 9; k++)
        w[k] = wmT[((g*64 + ic)*9 + k)*64 + oc];
      float xr[64];
      #pragma unroll
      for (int r = 0; r < 8; r++)
        #pragma unroll
        for (int cc = 0; cc < 8; cc++)
          xr[r*8 + cc] = sh[(rb + r)*14 + (cb + cc)][c];
      #pragma unroll
      for (int r = 0; r < 6; r++)
        #pragma unroll
        for (int cc = 0; cc < 6; cc++) {
          float a = acc[r*6 + cc];
          #pragma unroll
          for (int ky = 0; ky < 3; ky++)
            #pragma unroll
            for (int kx = 0; kx < 3; kx++)
              a = fmaf(xr[(r + ky)*8 + (cc + kx)], w[ky*3 + kx], a);
          acc[r*6 + cc] = a;
        }
    }
  }
  // BN + ReLU + tile-activity mask -> h in LDS
  int chg = (g < 6) ? g*64 + oc : (g - 6)*64 + oc;
  float sc, sht;
  if (g < 6) { sc = g_h[chg]*rsqrtf(v_h[chg] + EPSF); sht = b_h[chg] - m_h[chg]*sc; }
  else       { sc = g_a[chg]*rsqrtf(v_a[chg] + EPSF); sht = b_a[chg] - m_a[chg]*sc; }
  #pragma unroll
  for (int r = 0; r < 6; r++)
    #pragma unroll
    for (int cc = 0; cc < 6; cc++) {
      int hy = rb + r, hx = cb + cc;
      int gy = Y0 - 1 + hy, gx = X0 - 1 + hx;
      bool ok = (gy >= 0 && gy < HW && gx >= 0 && gx < HW &&
                 tmask[b*TC*TC + (gy/10)*TC + (gx/10)] != 0);
      float v = fmaxf(acc[r*6 + cc]*sc + sht, 0.f);
      h[hy*12 + hx][oc] = ok ? v : 0.f;
    }
  __syncthreads();
  // grouped out conv 64 -> Oc on the 10x10 tile
  if (tid < 100) {
    int py = tid / 10, pxx = tid % 10;
    float oacc[3] = {0.f, 0.f, 0.f};
    #pragma unroll 1
    for (int c4 = 0; c4 < 64; c4 += 4) {
      float4 hv[9];
      #pragma unroll
      for (int ky = 0; ky < 3; ky++)
        #pragma unroll
        for (int kx = 0; kx < 3; kx++)
          hv[ky*3 + kx] = *reinterpret_cast<const float4*>(&h[(py + ky)*12 + (pxx + kx)][c4]);
      #pragma unroll
      for (int o = 0; o < 3; o++) {
        if (o >= Oc) break;
        float a = oacc[o];
        #pragma unroll
        for (int t9 = 0; t9 < 9; t9++) {
          a = fmaf(hv[t9].x, w2T[((g*64 + c4 + 0)*9 + t9)*3 + o], a);
          a = fmaf(hv[t9].y, w2T[((g*64 + c4 + 1)*9 + t9)*3 + o], a);
          a = fmaf(hv[t9].z, w2T[((g*64 + c4 + 2)*9 + t9)*3 + o], a);
          a = fmaf(hv[t9].w, w2T[((g*64 + c4 + 3)*9 + t9)*3 + o], a);
        }
        oacc[o] = a;
      }
    }
    for (int o = 0; o < Oc; o++) {
      float bo = (g < 6) ? bias_hm[g*2 + o] : bias_attr[(g - 6)*3 + o];
      out[(((size_t)b*102 + cobase + o)*HW + (Y0 + py))*HW + (X0 + pxx)] = oacc[o] + bo;
    }
  }
}

extern "C" void kernel_launch(void* const* d_in, const int* in_sizes, int n_in,
                              void* d_out, int out_size, void* d_ws, size_t ws_size,
                              hipStream_t stream) {
  const float* x        = (const float*)d_in[0];
  const int*   tmask    = (const int*)  d_in[1];
  const float* w_s      = (const float*)d_in[2];
  const float* g_s      = (const float*)d_in[3];
  const float* b_s      = (const float*)d_in[4];
  const float* m_s      = (const float*)d_in[5];
  const float* v_s      = (const float*)d_in[6];
  const float* w_hm1    = (const float*)d_in[7];
  const float* g_h      = (const float*)d_in[8];
  const float* b_h      = (const float*)d_in[9];
  const float* m_h      = (const float*)d_in[10];
  const float* v_h      = (const float*)d_in[11];
  const float* w_hm2    = (const float*)d_in[12];
  const float* bias_hm  = (const float*)d_in[13];
  const float* w_attr1  = (const float*)d_in[14];
  const float* g_a      = (const float*)d_in[15];
  const float* b_a      = (const float*)d_in[16];
  const float* m_a      = (const float*)d_in[17];
  const float* v_a      = (const float*)d_in[18];
  const float* w_attr2  = (const float*)d_in[19];
  const float* bias_attr= (const float*)d_in[20];
  float* ws  = (float*)d_ws;
  float* out = (float*)d_out;

  int prep_total = N_WTS + N_WMT + N_W2T;            // 1,684,224
  prep_kernel<<<(prep_total + 255)/256, 256, 0, stream>>>(
      w_s, w_hm1, w_attr1, w_hm2, w_attr2, ws);
  shared_conv_kernel<<<2*TC*TC, 256, 0, stream>>>(
      x, tmask, ws + OFF_WTS, g_s, b_s, m_s, v_s, ws);
  branch_conv_kernel<<<2*TC*TC*36, 256, 0, stream>>>(
      ws, tmask, ws + OFF_WMT, ws + OFF_W2T,
      g_h, b_h, m_h, v_h, g_a, b_a, m_a, v_a, bias_hm, bias_attr, out);
}

// Round 6
// 658.744 us; speedup vs baseline: 4.3868x; 4.3868x over previous
//
#include <hip/hip_runtime.h>
#include <cstdint>

#define TC 18
#define HW 180
#define EPSF 1e-5f

typedef _Float16 half8 __attribute__((ext_vector_type(8)));
typedef float f32x4 __attribute__((ext_vector_type(4)));

// ws layout in halfs (_Float16)
#define OFF_SHB  0
#define N_SHB    (2*HW*HW*64)                  // 4,147,200
#define OFF_WSH  (N_SHB)                       // 4,147,200
#define N_WSH    (9*64*512)                    // 294,912
#define OFF_WM   (OFF_WSH + N_WSH)             // 4,442,112
#define N_WM     (36*9*64*64)                  // 1,327,104
#define OFF_W2   (OFF_WM + N_WM)               // 5,769,216
#define N_W2     (36*9*16*64)                  // 331,776

// ---------------- prep: repack weights to fp16 MFMA-friendly layouts ----------
__global__ __launch_bounds__(256) void prep_kernel(
    const float* __restrict__ w_s, const float* __restrict__ w_hm1,
    const float* __restrict__ w_attr1, const float* __restrict__ w_hm2,
    const float* __restrict__ w_attr2, _Float16* __restrict__ ws) {
  int i = blockIdx.x * 256 + threadIdx.x;
  if (i < N_WSH) {
    // wsh[tap][oc][ic512]
    int ic = i & 511, oc = (i >> 9) & 63, tap = i >> 15;
    ws[OFF_WSH + i] = (_Float16)w_s[((size_t)(oc*512 + ic))*9 + tap];
    return;
  }
  i -= N_WSH;
  if (i < N_WM) {
    // wm[g][tap][oc][ic64]
    int ic = i & 63, oc = (i >> 6) & 63, tap = (i >> 12) % 9, g = i / 36864;
    float v;
    if (g < 6) v = w_hm1[((size_t)((g*64 + oc)*64 + ic))*9 + tap];
    else       v = w_attr1[((size_t)(((g-6)*64 + oc)*64 + ic))*9 + tap];
    ws[OFF_WM + i] = (_Float16)v;
    return;
  }
  i -= N_WM;
  if (i < N_W2) {
    // w2[g][tap][oc16][ic64], zero-padded oc
    int ic = i & 63, oc = (i >> 6) & 15, tap = (i >> 10) % 9, g = i / 9216;
    float v = 0.f;
    if (g < 6) { if (oc < 2) v = w_hm2[((size_t)((g*2 + oc)*64 + ic))*9 + tap]; }
    else       { if (oc < 3) v = w_attr2[((size_t)(((g-6)*3 + oc)*64 + ic))*9 + tap]; }
    ws[OFF_W2 + i] = (_Float16)v;
  }
}

// ---------------- shared conv 512->64, MFMA fp16, out fp16 NHWC ---------------
__global__ __launch_bounds__(256, 4) void shared_conv_mfma(
    const float* __restrict__ x, const int* __restrict__ tmask,
    const _Float16* __restrict__ wsh,
    const float* __restrict__ g_s, const float* __restrict__ b_s,
    const float* __restrict__ m_s, const float* __restrict__ v_s,
    _Float16* __restrict__ shb) {
  int bid = blockIdx.x;
  int b = bid / (TC*TC), t = bid % (TC*TC);
  int ty = t / TC, tx = t % TC;
  int Y0 = ty*10, X0 = tx*10;
  int tid = threadIdx.x;
  _Float16* shp = shb + (size_t)b*HW*HW*64;
  bool active = tmask[b*TC*TC + t] != 0;
  if (!active) {
    for (int i = tid; i < 1600; i += 256) {      // 100 px * 16 q of 4 halfs
      int px = i >> 4, q = i & 15;
      int gy = Y0 + px/10, gx = X0 + px%10;
      *(float2*)(shp + ((size_t)(gy*HW + gx))*64 + q*4) = make_float2(0.f, 0.f);
    }
    return;
  }
  int nact = 0;
  #pragma unroll
  for (int dy = 0; dy < 3; dy++)
    #pragma unroll
    for (int dx = 0; dx < 3; dx++) {
      int tyy = ty+dy-1, txx = tx+dx-1;
      int a = (tyy>=0 && tyy<TC && txx>=0 && txx<TC) ? tmask[b*TC*TC + tyy*TC + txx] : 0;
      nact |= (a != 0) << (dy*3+dx);
    }
  __shared__ _Float16 sm[144*64];   // 18432 B, swizzled rows of 128 B
  int lane = tid & 63, w = tid >> 6;
  int mh = w >> 1, nh = w & 1;
  int l15 = lane & 15, l4 = lane >> 4;
  // per-fi A-row bases (out px -> input row base)
  int r0[4];
  #pragma unroll
  for (int fi = 0; fi < 4; fi++) {
    int f = mh + fi*2;
    int p = f*16 + l15; if (p > 99) p = 99;
    r0[fi] = (p/10)*12 + (p%10);
  }
  f32x4 acc[4][2];
  #pragma unroll
  for (int fi = 0; fi < 4; fi++)
    #pragma unroll
    for (int j = 0; j < 2; j++) acc[fi][j] = (f32x4)0.f;

  for (int ck = 0; ck < 8; ck++) {
    __syncthreads();
    for (int i = tid; i < 1152; i += 256) {     // 144 px * 8 slots
      int px = i % 144, s8 = i / 144;
      int ry = px/12, rx = px%12;
      int gy = Y0-1+ry, gx = X0-1+rx;
      int selr = (ry==0)?0:((ry<=10)?1:2);
      int selc = (rx==0)?0:((rx<=10)?1:2);
      bool ok = (gy>=0 && gy<HW && gx>=0 && gx<HW) && ((nact>>(selr*3+selc))&1);
      half8 hv;
      #pragma unroll
      for (int j = 0; j < 8; j++) hv[j] = (_Float16)0.f;
      if (ok) {
        const float* xp = x + (((size_t)b*512 + ck*64 + s8*8)*HW + gy)*HW + gx;
        #pragma unroll
        for (int j = 0; j < 8; j++) hv[j] = (_Float16)xp[(size_t)j*HW*HW];
      }
      *(half8*)((char*)sm + px*128 + (((s8 ^ (px&7)) & 7)<<4)) = hv;
    }
    __syncthreads();
    for (int tap = 0; tap < 9; tap++) {
      int ky = tap/3, kx = tap%3;
      int radd = ky*12 + kx;
      #pragma unroll
      for (int ks = 0; ks < 2; ks++) {
        half8 bf[2];
        #pragma unroll
        for (int j = 0; j < 2; j++) {
          int oc = (nh*2 + j)*16 + l15;
          bf[j] = *(const half8*)(wsh + (size_t)(tap*64 + oc)*512 + ck*64 + ks*32 + l4*8);
        }
        #pragma unroll
        for (int fi = 0; fi < 4; fi++) {
          int f = mh + fi*2;
          if (f < 7) {
            int r = r0[fi] + radd;
            half8 af = *(const half8*)((const char*)sm + (r<<7) + ((((ks*4 + l4) ^ r) & 7)<<4));
            acc[fi][0] = __builtin_amdgcn_mfma_f32_16x16x32_f16(af, bf[0], acc[fi][0], 0, 0, 0);
            acc[fi][1] = __builtin_amdgcn_mfma_f32_16x16x32_f16(af, bf[1], acc[fi][1], 0, 0, 0);
          }
        }
      }
    }
  }
  // BN + ReLU -> fp16 NHWC
  float sc_[2], sh_[2];
  #pragma unroll
  for (int j = 0; j < 2; j++) {
    int oc = (nh*2 + j)*16 + l15;
    float s = g_s[oc] * rsqrtf(v_s[oc] + EPSF);
    sc_[j] = s; sh_[j] = b_s[oc] - m_s[oc]*s;
  }
  #pragma unroll
  for (int fi = 0; fi < 4; fi++) {
    int f = mh + fi*2;
    if (f < 7) {
      #pragma unroll
      for (int j = 0; j < 2; j++) {
        int oc = (nh*2 + j)*16 + l15;
        #pragma unroll
        for (int r = 0; r < 4; r++) {
          int p = f*16 + l4*4 + r;
          if (p < 100) {
            float v = fmaxf(fmaf(acc[fi][j][r], sc_[j], sh_[j]), 0.f);
            int gy = Y0 + p/10, gx = X0 + p%10;
            shp[((size_t)(gy*HW + gx))*64 + oc] = (_Float16)v;
          }
        }
      }
    }
  }
}

// -------- branch: per (tile,group) mid conv 64->64 + grouped 64->{2,3} -------
__global__ __launch_bounds__(256, 3) void branch_conv_mfma(
    const _Float16* __restrict__ shb, const int* __restrict__ tmask,
    const _Float16* __restrict__ wm, const _Float16* __restrict__ w2,
    const float* __restrict__ g_h, const float* __restrict__ b_h,
    const float* __restrict__ m_h, const float* __restrict__ v_h,
    const float* __restrict__ g_a, const float* __restrict__ b_a,
    const float* __restrict__ m_a, const float* __restrict__ v_a,
    const float* __restrict__ bias_hm, const float* __restrict__ bias_attr,
    float* __restrict__ out) {
  int bid = blockIdx.x;
  int g = bid % 36;
  int t = bid / 36;
  int b = t / (TC*TC); t %= (TC*TC);
  int ty = t / TC, tx = t % TC;
  int Y0 = ty*10, X0 = tx*10;
  int tid = threadIdx.x;
  int Oc = (g < 6) ? 2 : 3;
  int cobase = (g < 6) ? g*2 : 12 + (g-6)*3;
  bool active = tmask[b*TC*TC + ty*TC + tx] != 0;
  if (!active) {
    if (tid < 100) {
      int py = tid/10, px = tid%10;
      for (int o = 0; o < Oc; o++)
        out[(((size_t)b*102 + cobase + o)*HW + (Y0+py))*HW + (X0+px)] = 0.f;
    }
    return;
  }
  int nact = 0;
  #pragma unroll
  for (int dy = 0; dy < 3; dy++)
    #pragma unroll
    for (int dx = 0; dx < 3; dx++) {
      int tyy = ty+dy-1, txx = tx+dx-1;
      int a = (tyy>=0 && tyy<TC && txx>=0 && txx<TC) ? tmask[b*TC*TC + tyy*TC + txx] : 0;
      nact |= (a != 0) << (dy*3+dx);
    }
  __shared__ _Float16 sm[196*64];   // 25088 B; h aliases rows 0..143 later
  const _Float16* shp = shb + (size_t)b*HW*HW*64;
  int lane = tid & 63, w = tid >> 6;
  int mh = w >> 1, nh = w & 1;
  int l15 = lane & 15, l4 = lane >> 4;

  // stage 14x14x64 fp16 tile (swizzled)
  for (int i = tid; i < 1568; i += 256) {       // 196 px * 8 slots
    int px = i >> 3, s8 = i & 7;
    int ry = px/14, rx = px%14;
    int gy = Y0-2+ry, gx = X0-2+rx;
    half8 hv;
    if (gy>=0 && gy<HW && gx>=0 && gx<HW)
      hv = *(const half8*)(shp + ((size_t)(gy*HW + gx))*64 + s8*8);
    else {
      #pragma unroll
      for (int j = 0; j < 8; j++) hv[j] = (_Float16)0.f;
    }
    *(half8*)((char*)sm + px*128 + (((s8 ^ px) & 7)<<4)) = hv;
  }
  __syncthreads();

  // mid conv: M=144 (9 frags), N=64, K=576
  int r0[5];
  #pragma unroll
  for (int fi = 0; fi < 5; fi++) {
    int f = mh + fi*2;
    int p = f*16 + l15; if (p > 143) p = 143;
    r0[fi] = (p/12)*14 + (p%12);
  }
  f32x4 acc[5][2];
  #pragma unroll
  for (int fi = 0; fi < 5; fi++)
    #pragma unroll
    for (int j = 0; j < 2; j++) acc[fi][j] = (f32x4)0.f;

  const _Float16* wmg = wm + (size_t)g*9*64*64;
  for (int tap = 0; tap < 9; tap++) {
    int radd = (tap/3)*14 + (tap%3);
    #pragma unroll
    for (int ks = 0; ks < 2; ks++) {
      half8 bf[2];
      #pragma unroll
      for (int j = 0; j < 2; j++) {
        int oc = (nh*2 + j)*16 + l15;
        bf[j] = *(const half8*)(wmg + (size_t)(tap*64 + oc)*64 + ks*32 + l4*8);
      }
      #pragma unroll
      for (int fi = 0; fi < 5; fi++) {
        int f = mh + fi*2;
        if (f < 9) {
          int r = r0[fi] + radd;
          half8 af = *(const half8*)((const char*)sm + (r<<7) + ((((ks*4 + l4) ^ r) & 7)<<4));
          acc[fi][0] = __builtin_amdgcn_mfma_f32_16x16x32_f16(af, bf[0], acc[fi][0], 0, 0, 0);
          acc[fi][1] = __builtin_amdgcn_mfma_f32_16x16x32_f16(af, bf[1], acc[fi][1], 0, 0, 0);
        }
      }
    }
  }
  __syncthreads();   // all A-reads done before h overwrites sm

  // BN + ReLU + pixel mask -> h fp16 into sm rows 0..143 (swizzled)
  {
    float sc_[2], sh_[2];
    #pragma unroll
    for (int j = 0; j < 2; j++) {
      int ocl = (nh*2 + j)*16 + l15;
      float s, sh2;
      if (g < 6) { int c = g*64 + ocl;     s = g_h[c]*rsqrtf(v_h[c]+EPSF); sh2 = b_h[c] - m_h[c]*s; }
      else       { int c = (g-6)*64 + ocl; s = g_a[c]*rsqrtf(v_a[c]+EPSF); sh2 = b_a[c] - m_a[c]*s; }
      sc_[j] = s; sh_[j] = sh2;
    }
    #pragma unroll
    for (int fi = 0; fi < 5; fi++) {
      int f = mh + fi*2;
      if (f < 9) {
        #pragma unroll
        for (int j = 0; j < 2; j++) {
          int oc = (nh*2 + j)*16 + l15;
          #pragma unroll
          for (int r = 0; r < 4; r++) {
            int px = f*16 + l4*4 + r;
            int hy = px/12, hx = px%12;
            int selr = (hy==0)?0:((hy<=10)?1:2);
            int selc = (hx==0)?0:((hx<=10)?1:2);
            float v = fmaxf(fmaf(acc[fi][j][r], sc_[j], sh_[j]), 0.f);
            if (!((nact>>(selr*3+selc))&1)) v = 0.f;
            *(_Float16*)((char*)sm + (px<<7) + ((((oc>>3) ^ px) & 7)<<4) + (oc&7)*2) = (_Float16)v;
          }
        }
      }
    }
  }
  __syncthreads();

  // out conv: M=100 (7 frags), N=16 (Oc used), K=576
  int r0b[2];
  #pragma unroll
  for (int fi = 0; fi < 2; fi++) {
    int f = w + fi*4;
    int p = f*16 + l15; if (p > 99) p = 99;
    r0b[fi] = (p/10)*12 + (p%10);
  }
  f32x4 acc2[2];
  acc2[0] = (f32x4)0.f; acc2[1] = (f32x4)0.f;
  const _Float16* w2g = w2 + (size_t)g*9*16*64;
  for (int tap = 0; tap < 9; tap++) {
    int radd = (tap/3)*12 + (tap%3);
    #pragma unroll
    for (int ks = 0; ks < 2; ks++) {
      half8 bf = *(const half8*)(w2g + (size_t)(tap*16 + l15)*64 + ks*32 + l4*8);
      #pragma unroll
      for (int fi = 0; fi < 2; fi++) {
        int f = w + fi*4;
        if (f < 7) {
          int r = r0b[fi] + radd;
          half8 af = *(const half8*)((const char*)sm + (r<<7) + ((((ks*4 + l4) ^ r) & 7)<<4));
          acc2[fi] = __builtin_amdgcn_mfma_f32_16x16x32_f16(af, bf, acc2[fi], 0, 0, 0);
        }
      }
    }
  }
  // store
  int oc2 = l15;
  float bo = 0.f;
  if (oc2 < Oc) bo = (g < 6) ? bias_hm[g*2 + oc2] : bias_attr[(g-6)*3 + oc2];
  #pragma unroll
  for (int fi = 0; fi < 2; fi++) {
    int f = w + fi*4;
    if (f < 7 && oc2 < Oc) {
      #pragma unroll
      for (int r = 0; r < 4; r++) {
        int p = f*16 + l4*4 + r;
        if (p < 100) {
          int gy = Y0 + p/10, gx = X0 + p%10;
          out[(((size_t)b*102 + cobase + oc2)*HW + gy)*HW + gx] = acc2[fi][r] + bo;
        }
      }
    }
  }
}

extern "C" void kernel_launch(void* const* d_in, const int* in_sizes, int n_in,
                              void* d_out, int out_size, void* d_ws, size_t ws_size,
                              hipStream_t stream) {
  const float* x        = (const float*)d_in[0];
  const int*   tmask    = (const int*)  d_in[1];
  const float* w_s      = (const float*)d_in[2];
  const float* g_s      = (const float*)d_in[3];
  const float* b_s      = (const float*)d_in[4];
  const float* m_s      = (const float*)d_in[5];
  const float* v_s      = (const float*)d_in[6];
  const float* w_hm1    = (const float*)d_in[7];
  const float* g_h      = (const float*)d_in[8];
  const float* b_h      = (const float*)d_in[9];
  const float* m_h      = (const float*)d_in[10];
  const float* v_h      = (const float*)d_in[11];
  const float* w_hm2    = (const float*)d_in[12];
  const float* bias_hm  = (const float*)d_in[13];
  const float* w_attr1  = (const float*)d_in[14];
  const float* g_a      = (const float*)d_in[15];
  const float* b_a      = (const float*)d_in[16];
  const float* m_a      = (const float*)d_in[17];
  const float* v_a      = (const float*)d_in[18];
  const float* w_attr2  = (const float*)d_in[19];
  const float* bias_attr= (const float*)d_in[20];
  _Float16* ws = (_Float16*)d_ws;
  float* out = (float*)d_out;

  int prep_total = N_WSH + N_WM + N_W2;
  prep_kernel<<<(prep_total + 255)/256, 256, 0, stream>>>(
      w_s, w_hm1, w_attr1, w_hm2, w_attr2, ws);
  shared_conv_mfma<<<2*TC*TC, 256, 0, stream>>>(
      x, tmask, ws + OFF_WSH, g_s, b_s, m_s, v_s, ws + OFF_SHB);
  branch_conv_mfma<<<2*TC*TC*36, 256, 0, stream>>>(
      ws + OFF_SHB, tmask, ws + OFF_WM, ws + OFF_W2,
      g_h, b_h, m_h, v_h, g_a, b_a, m_a, v_a, bias_hm, bias_attr, out);
}

// Round 7
// 658.550 us; speedup vs baseline: 4.3881x; 1.0003x over previous
//
#include <hip/hip_runtime.h>
#include <cstdint>

#define TC 18
#define HW 180
#define EPSF 1e-5f

typedef _Float16 half8 __attribute__((ext_vector_type(8)));
typedef _Float16 half4 __attribute__((ext_vector_type(4)));
typedef float f32x4 __attribute__((ext_vector_type(4)));

// ws layout in halfs (_Float16)
#define OFF_SHB  0
#define N_SHB    (2*HW*HW*64)                  // 4,147,200
#define OFF_WSH  (N_SHB)                       // 4,147,200
#define N_WSH    (9*64*512)                    // 294,912
#define OFF_WM   (OFF_WSH + N_WSH)             // 4,442,112
#define N_WM     (36*9*64*64)                  // 1,327,104
#define OFF_W2   (OFF_WM + N_WM)               // 5,769,216
#define N_W2     (36*9*16*64)                  // 331,776

// ---------------- prep: repack weights to fp16 MFMA-friendly layouts ----------
__global__ __launch_bounds__(256) void prep_kernel(
    const float* __restrict__ w_s, const float* __restrict__ w_hm1,
    const float* __restrict__ w_attr1, const float* __restrict__ w_hm2,
    const float* __restrict__ w_attr2, _Float16* __restrict__ ws) {
  int i = blockIdx.x * 256 + threadIdx.x;
  if (i < N_WSH) {
    // wsh[tap][oc][ic512]
    int ic = i & 511, oc = (i >> 9) & 63, tap = i >> 15;
    ws[OFF_WSH + i] = (_Float16)w_s[((size_t)(oc*512 + ic))*9 + tap];
    return;
  }
  i -= N_WSH;
  if (i < N_WM) {
    // wm[g][tap][oc][ic64]
    int ic = i & 63, oc = (i >> 6) & 63, tap = (i >> 12) % 9, g = i / 36864;
    float v;
    if (g < 6) v = w_hm1[((size_t)((g*64 + oc)*64 + ic))*9 + tap];
    else       v = w_attr1[((size_t)(((g-6)*64 + oc)*64 + ic))*9 + tap];
    ws[OFF_WM + i] = (_Float16)v;
    return;
  }
  i -= N_WM;
  if (i < N_W2) {
    // w2[g][tap][oc16][ic64], zero-padded oc
    int ic = i & 63, oc = (i >> 6) & 15, tap = (i >> 10) % 9, g = i / 9216;
    float v = 0.f;
    if (g < 6) { if (oc < 2) v = w_hm2[((size_t)((g*2 + oc)*64 + ic))*9 + tap]; }
    else       { if (oc < 3) v = w_attr2[((size_t)(((g-6)*3 + oc)*64 + ic))*9 + tap]; }
    ws[OFF_W2 + i] = (_Float16)v;
  }
}

// ---------------- shared conv 512->64, MFMA fp16 (swapped: D = W·X), out fp16 NHWC
__global__ __launch_bounds__(256, 4) void shared_conv_mfma(
    const float* __restrict__ x, const int* __restrict__ tmask,
    const _Float16* __restrict__ wsh,
    const float* __restrict__ g_s, const float* __restrict__ b_s,
    const float* __restrict__ m_s, const float* __restrict__ v_s,
    _Float16* __restrict__ shb) {
  int bid = blockIdx.x;
  int b = bid / (TC*TC), t = bid % (TC*TC);
  int ty = t / TC, tx = t % TC;
  int Y0 = ty*10, X0 = tx*10;
  int tid = threadIdx.x;
  _Float16* shp = shb + (size_t)b*HW*HW*64;
  bool active = tmask[b*TC*TC + t] != 0;
  if (!active) {
    for (int i = tid; i < 1600; i += 256) {      // 100 px * 16 q of 4 halfs
      int px = i >> 4, q = i & 15;
      int gy = Y0 + px/10, gx = X0 + px%10;
      *(float2*)(shp + ((size_t)(gy*HW + gx))*64 + q*4) = make_float2(0.f, 0.f);
    }
    return;
  }
  int nact = 0;
  #pragma unroll
  for (int dy = 0; dy < 3; dy++)
    #pragma unroll
    for (int dx = 0; dx < 3; dx++) {
      int tyy = ty+dy-1, txx = tx+dx-1;
      int a = (tyy>=0 && tyy<TC && txx>=0 && txx<TC) ? tmask[b*TC*TC + tyy*TC + txx] : 0;
      nact |= (a != 0) << (dy*3+dx);
    }
  __shared__ _Float16 sm[144*64];   // 18432 B, swizzled rows of 128 B
  int lane = tid & 63, w = tid >> 6;
  int mh = w >> 1, nh = w & 1;
  int l15 = lane & 15, l4 = lane >> 4;
  // per-fi A-row bases (out px -> input row base); px = f*16 + l15
  int r0[4];
  #pragma unroll
  for (int fi = 0; fi < 4; fi++) {
    int f = mh + fi*2;
    int p = f*16 + l15; if (p > 99) p = 99;
    r0[fi] = (p/10)*12 + (p%10);
  }
  f32x4 acc[4][2];
  #pragma unroll
  for (int fi = 0; fi < 4; fi++)
    #pragma unroll
    for (int j = 0; j < 2; j++) acc[fi][j] = (f32x4)0.f;

  for (int ck = 0; ck < 8; ck++) {
    __syncthreads();
    for (int i = tid; i < 1152; i += 256) {     // 144 px * 8 slots
      int px = i % 144, s8 = i / 144;
      int ry = px/12, rx = px%12;
      int gy = Y0-1+ry, gx = X0-1+rx;
      int selr = (ry==0)?0:((ry<=10)?1:2);
      int selc = (rx==0)?0:((rx<=10)?1:2);
      bool ok = (gy>=0 && gy<HW && gx>=0 && gx<HW) && ((nact>>(selr*3+selc))&1);
      half8 hv;
      #pragma unroll
      for (int j = 0; j < 8; j++) hv[j] = (_Float16)0.f;
      if (ok) {
        const float* xp = x + (((size_t)b*512 + ck*64 + s8*8)*HW + gy)*HW + gx;
        #pragma unroll
        for (int j = 0; j < 8; j++) hv[j] = (_Float16)xp[(size_t)j*HW*HW];
      }
      *(half8*)((char*)sm + px*128 + (((s8 ^ (px&7)) & 7)<<4)) = hv;
    }
    __syncthreads();
    for (int tap = 0; tap < 9; tap++) {
      int ky = tap/3, kx = tap%3;
      int radd = ky*12 + kx;
      #pragma unroll
      for (int ks = 0; ks < 2; ks++) {
        half8 bf[2];
        #pragma unroll
        for (int j = 0; j < 2; j++) {
          int oc = (nh*2 + j)*16 + l15;
          bf[j] = *(const half8*)(wsh + (size_t)(tap*64 + oc)*512 + ck*64 + ks*32 + l4*8);
        }
        #pragma unroll
        for (int fi = 0; fi < 4; fi++) {
          int f = mh + fi*2;
          if (f < 7) {
            int r = r0[fi] + radd;
            half8 af = *(const half8*)((const char*)sm + (r<<7) + ((((ks*4 + l4) ^ r) & 7)<<4));
            // swapped: D[oc][px] — lane holds 4 consecutive oc at one px
            acc[fi][0] = __builtin_amdgcn_mfma_f32_16x16x32_f16(bf[0], af, acc[fi][0], 0, 0, 0);
            acc[fi][1] = __builtin_amdgcn_mfma_f32_16x16x32_f16(bf[1], af, acc[fi][1], 0, 0, 0);
          }
        }
      }
    }
  }
  // BN + ReLU -> fp16 NHWC; lane: px = f*16+l15, oc = (nh*2+j)*16 + l4*4 + r
  float sc4[2][4], sh4[2][4];
  #pragma unroll
  for (int j = 0; j < 2; j++) {
    int ocb = (nh*2 + j)*16 + l4*4;
    float4 gg = *(const float4*)&g_s[ocb];
    float4 vv = *(const float4*)&v_s[ocb];
    float4 bb = *(const float4*)&b_s[ocb];
    float4 mm = *(const float4*)&m_s[ocb];
    float gA[4] = {gg.x,gg.y,gg.z,gg.w}, vA[4] = {vv.x,vv.y,vv.z,vv.w};
    float bA[4] = {bb.x,bb.y,bb.z,bb.w}, mA[4] = {mm.x,mm.y,mm.z,mm.w};
    #pragma unroll
    for (int r = 0; r < 4; r++) {
      float s = gA[r] * rsqrtf(vA[r] + EPSF);
      sc4[j][r] = s; sh4[j][r] = bA[r] - mA[r]*s;
    }
  }
  #pragma unroll
  for (int fi = 0; fi < 4; fi++) {
    int f = mh + fi*2;
    if (f < 7) {
      int p = f*16 + l15;
      if (p < 100) {
        int gy = Y0 + p/10, gx = X0 + p%10;
        _Float16* dst = shp + ((size_t)(gy*HW + gx))*64;
        #pragma unroll
        for (int j = 0; j < 2; j++) {
          int ocb = (nh*2 + j)*16 + l4*4;
          half4 hv;
          #pragma unroll
          for (int r = 0; r < 4; r++)
            hv[r] = (_Float16)fmaxf(fmaf(acc[fi][j][r], sc4[j][r], sh4[j][r]), 0.f);
          *(half4*)(dst + ocb) = hv;
        }
      }
    }
  }
}

// -------- branch: per (tile,group) mid conv 64->64 + grouped 64->{2,3} -------
__global__ __launch_bounds__(256, 3) void branch_conv_mfma(
    const _Float16* __restrict__ shb, const int* __restrict__ tmask,
    const _Float16* __restrict__ wm, const _Float16* __restrict__ w2,
    const float* __restrict__ g_h, const float* __restrict__ b_h,
    const float* __restrict__ m_h, const float* __restrict__ v_h,
    const float* __restrict__ g_a, const float* __restrict__ b_a,
    const float* __restrict__ m_a, const float* __restrict__ v_a,
    const float* __restrict__ bias_hm, const float* __restrict__ bias_attr,
    float* __restrict__ out) {
  int bid = blockIdx.x;
  int g = bid % 36;
  int t = bid / 36;
  int b = t / (TC*TC); t %= (TC*TC);
  int ty = t / TC, tx = t % TC;
  int Y0 = ty*10, X0 = tx*10;
  int tid = threadIdx.x;
  int Oc = (g < 6) ? 2 : 3;
  int cobase = (g < 6) ? g*2 : 12 + (g-6)*3;
  bool active = tmask[b*TC*TC + ty*TC + tx] != 0;
  if (!active) {
    if (tid < 100) {
      int py = tid/10, px = tid%10;
      for (int o = 0; o < Oc; o++)
        out[(((size_t)b*102 + cobase + o)*HW + (Y0+py))*HW + (X0+px)] = 0.f;
    }
    return;
  }
  int nact = 0;
  #pragma unroll
  for (int dy = 0; dy < 3; dy++)
    #pragma unroll
    for (int dx = 0; dx < 3; dx++) {
      int tyy = ty+dy-1, txx = tx+dx-1;
      int a = (tyy>=0 && tyy<TC && txx>=0 && txx<TC) ? tmask[b*TC*TC + tyy*TC + txx] : 0;
      nact |= (a != 0) << (dy*3+dx);
    }
  __shared__ _Float16 sm[196*64];   // 25088 B; h aliases rows 0..143 later
  const _Float16* shp = shb + (size_t)b*HW*HW*64;
  int lane = tid & 63, w = tid >> 6;
  int mh = w >> 1, nh = w & 1;
  int l15 = lane & 15, l4 = lane >> 4;

  // stage 14x14x64 fp16 tile (swizzled)
  for (int i = tid; i < 1568; i += 256) {       // 196 px * 8 slots
    int px = i >> 3, s8 = i & 7;
    int ry = px/14, rx = px%14;
    int gy = Y0-2+ry, gx = X0-2+rx;
    half8 hv;
    if (gy>=0 && gy<HW && gx>=0 && gx<HW)
      hv = *(const half8*)(shp + ((size_t)(gy*HW + gx))*64 + s8*8);
    else {
      #pragma unroll
      for (int j = 0; j < 8; j++) hv[j] = (_Float16)0.f;
    }
    *(half8*)((char*)sm + px*128 + (((s8 ^ px) & 7)<<4)) = hv;
  }
  __syncthreads();

  // mid conv: M(oc)=64, N(px)=144 (9 frags), K=576  (swapped operands)
  int r0[5];
  #pragma unroll
  for (int fi = 0; fi < 5; fi++) {
    int f = mh + fi*2;
    int p = f*16 + l15; if (p > 143) p = 143;
    r0[fi] = (p/12)*14 + (p%12);
  }
  f32x4 acc[5][2];
  #pragma unroll
  for (int fi = 0; fi < 5; fi++)
    #pragma unroll
    for (int j = 0; j < 2; j++) acc[fi][j] = (f32x4)0.f;

  const _Float16* wmg = wm + (size_t)g*9*64*64;
  for (int tap = 0; tap < 9; tap++) {
    int radd = (tap/3)*14 + (tap%3);
    #pragma unroll
    for (int ks = 0; ks < 2; ks++) {
      half8 bf[2];
      #pragma unroll
      for (int j = 0; j < 2; j++) {
        int oc = (nh*2 + j)*16 + l15;
        bf[j] = *(const half8*)(wmg + (size_t)(tap*64 + oc)*64 + ks*32 + l4*8);
      }
      #pragma unroll
      for (int fi = 0; fi < 5; fi++) {
        int f = mh + fi*2;
        if (f < 9) {
          int r = r0[fi] + radd;
          half8 af = *(const half8*)((const char*)sm + (r<<7) + ((((ks*4 + l4) ^ r) & 7)<<4));
          acc[fi][0] = __builtin_amdgcn_mfma_f32_16x16x32_f16(bf[0], af, acc[fi][0], 0, 0, 0);
          acc[fi][1] = __builtin_amdgcn_mfma_f32_16x16x32_f16(bf[1], af, acc[fi][1], 0, 0, 0);
        }
      }
    }
  }
  __syncthreads();   // all A-reads done before h overwrites sm

  // BN + ReLU + pixel mask -> h fp16 into sm rows 0..143 (swizzled)
  // lane holds px = f*16 + l15, oc = (nh*2+j)*16 + l4*4 + r  -> 8-B writes
  {
    float sc4[2][4], sh4[2][4];
    #pragma unroll
    for (int j = 0; j < 2; j++) {
      int ocb = (nh*2 + j)*16 + l4*4;
      int c = ((g < 6) ? g*64 : (g-6)*64) + ocb;
      const float* Gp = (g < 6) ? g_h : g_a;
      const float* Vp = (g < 6) ? v_h : v_a;
      const float* Bp = (g < 6) ? b_h : b_a;
      const float* Mp = (g < 6) ? m_h : m_a;
      float4 gg = *(const float4*)&Gp[c];
      float4 vv = *(const float4*)&Vp[c];
      float4 bb = *(const float4*)&Bp[c];
      float4 mm = *(const float4*)&Mp[c];
      float gA[4] = {gg.x,gg.y,gg.z,gg.w}, vA[4] = {vv.x,vv.y,vv.z,vv.w};
      float bA[4] = {bb.x,bb.y,bb.z,bb.w}, mA[4] = {mm.x,mm.y,mm.z,mm.w};
      #pragma unroll
      for (int r = 0; r < 4; r++) {
        float s = gA[r] * rsqrtf(vA[r] + EPSF);
        sc4[j][r] = s; sh4[j][r] = bA[r] - mA[r]*s;
      }
    }
    #pragma unroll
    for (int fi = 0; fi < 5; fi++) {
      int f = mh + fi*2;
      if (f < 9) {
        int px = f*16 + l15;                     // 0..143, always valid
        int hy = px/12, hx = px - hy*12;
        int selr = (hy==0)?0:((hy<=10)?1:2);
        int selc = (hx==0)?0:((hx<=10)?1:2);
        bool ok = (nact>>(selr*3+selc)) & 1;
        #pragma unroll
        for (int j = 0; j < 2; j++) {
          int ocb = (nh*2 + j)*16 + l4*4;
          half4 hv;
          #pragma unroll
          for (int r = 0; r < 4; r++) {
            float v = ok ? fmaxf(fmaf(acc[fi][j][r], sc4[j][r], sh4[j][r]), 0.f) : 0.f;
            hv[r] = (_Float16)v;
          }
          *(half4*)((char*)sm + (px<<7) + ((((ocb>>3) ^ px) & 7)<<4) + (ocb&7)*2) = hv;
        }
      }
    }
  }
  __syncthreads();

  // out conv: M(oc)=16 (Oc used), N(px)=100 (7 frags), K=576 (swapped)
  int r0b[2];
  #pragma unroll
  for (int fi = 0; fi < 2; fi++) {
    int f = w + fi*4;
    int p = f*16 + l15; if (p > 99) p = 99;
    r0b[fi] = (p/10)*12 + (p%10);
  }
  f32x4 acc2[2];
  acc2[0] = (f32x4)0.f; acc2[1] = (f32x4)0.f;
  const _Float16* w2g = w2 + (size_t)g*9*16*64;
  for (int tap = 0; tap < 9; tap++) {
    int radd = (tap/3)*12 + (tap%3);
    #pragma unroll
    for (int ks = 0; ks < 2; ks++) {
      half8 bf = *(const half8*)(w2g + (size_t)(tap*16 + l15)*64 + ks*32 + l4*8);
      #pragma unroll
      for (int fi = 0; fi < 2; fi++) {
        int f = w + fi*4;
        if (f < 7) {
          int r = r0b[fi] + radd;
          half8 af = *(const half8*)((const char*)sm + (r<<7) + ((((ks*4 + l4) ^ r) & 7)<<4));
          acc2[fi] = __builtin_amdgcn_mfma_f32_16x16x32_f16(bf, af, acc2[fi], 0, 0, 0);
        }
      }
    }
  }
  // store: lane l4==0 holds oc = reg (0..3), px = f*16 + l15 (row-coalesced)
  float bo[3];
  #pragma unroll
  for (int o = 0; o < 3; o++)
    bo[o] = (o < Oc) ? ((g < 6) ? bias_hm[g*2 + o] : bias_attr[(g-6)*3 + o]) : 0.f;
  #pragma unroll
  for (int fi = 0; fi < 2; fi++) {
    int f = w + fi*4;
    int p = f*16 + l15;
    if (f < 7 && l4 == 0 && p < 100) {
      int gy = Y0 + p/10, gx = X0 + p%10;
      float* op = out + (((size_t)b*102 + cobase)*HW + gy)*HW + gx;
      #pragma unroll
      for (int o = 0; o < 3; o++)
        if (o < Oc) op[(size_t)o*HW*HW] = acc2[fi][o] + bo[o];
    }
  }
}

extern "C" void kernel_launch(void* const* d_in, const int* in_sizes, int n_in,
                              void* d_out, int out_size, void* d_ws, size_t ws_size,
                              hipStream_t stream) {
  const float* x        = (const float*)d_in[0];
  const int*   tmask    = (const int*)  d_in[1];
  const float* w_s      = (const float*)d_in[2];
  const float* g_s      = (const float*)d_in[3];
  const float* b_s      = (const float*)d_in[4];
  const float* m_s      = (const float*)d_in[5];
  const float* v_s      = (const float*)d_in[6];
  const float* w_hm1    = (const float*)d_in[7];
  const float* g_h      = (const float*)d_in[8];
  const float* b_h      = (const float*)d_in[9];
  const float* m_h      = (const float*)d_in[10];
  const float* v_h      = (const float*)d_in[11];
  const float* w_hm2    = (const float*)d_in[12];
  const float* bias_hm  = (const float*)d_in[13];
  const float* w_attr1  = (const float*)d_in[14];
  const float* g_a      = (const float*)d_in[15];
  const float* b_a      = (const float*)d_in[16];
  const float* m_a      = (const float*)d_in[17];
  const float* v_a      = (const float*)d_in[18];
  const float* w_attr2  = (const float*)d_in[19];
  const float* bias_attr= (const float*)d_in[20];
  _Float16* ws = (_Float16*)d_ws;
  float* out = (float*)d_out;

  int prep_total = N_WSH + N_WM + N_W2;
  prep_kernel<<<(prep_total + 255)/256, 256, 0, stream>>>(
      w_s, w_hm1, w_attr1, w_hm2, w_attr2, ws);
  shared_conv_mfma<<<2*TC*TC, 256, 0, stream>>>(
      x, tmask, ws + OFF_WSH, g_s, b_s, m_s, v_s, ws + OFF_SHB);
  branch_conv_mfma<<<2*TC*TC*36, 256, 0, stream>>>(
      ws + OFF_SHB, tmask, ws + OFF_WM, ws + OFF_W2,
      g_h, b_h, m_h, v_h, g_a, b_a, m_a, v_a, bias_hm, bias_attr, out);
}

// Round 10
// 655.432 us; speedup vs baseline: 4.4090x; 1.0048x over previous
//
#include <hip/hip_runtime.h>
#include <cstdint>

#define TC 18
#define HW 180
#define EPSF 1e-5f

typedef _Float16 half8 __attribute__((ext_vector_type(8)));
typedef _Float16 half4 __attribute__((ext_vector_type(4)));
typedef float f32x4 __attribute__((ext_vector_type(4)));

// ws layout in halfs (_Float16)
#define OFF_SHB  0
#define N_SHB    (2*HW*HW*64)                  // 4,147,200
#define OFF_WSH  (N_SHB)                       // 4,147,200
#define N_WSH    (9*64*512)                    // 294,912
#define OFF_WM   (OFF_WSH + N_WSH)             // 4,442,112
#define N_WM     (36*9*64*64)                  // 1,327,104
#define OFF_W2   (OFF_WM + N_WM)               // 5,769,216
#define N_W2     (36*9*16*64)                  // 331,776

// ---------------- prep: repack weights to fp16 MFMA-friendly layouts ----------
__global__ __launch_bounds__(256) void prep_kernel(
    const float* __restrict__ w_s, const float* __restrict__ w_hm1,
    const float* __restrict__ w_attr1, const float* __restrict__ w_hm2,
    const float* __restrict__ w_attr2, _Float16* __restrict__ ws) {
  int i = blockIdx.x * 256 + threadIdx.x;
  if (i < N_WSH) {
    // wsh[tap][oc][ic512]
    int ic = i & 511, oc = (i >> 9) & 63, tap = i >> 15;
    ws[OFF_WSH + i] = (_Float16)w_s[((size_t)(oc*512 + ic))*9 + tap];
    return;
  }
  i -= N_WSH;
  if (i < N_WM) {
    // wm[g][tap][oc][ic64]
    int ic = i & 63, oc = (i >> 6) & 63, tap = (i >> 12) % 9, g = i / 36864;
    float v;
    if (g < 6) v = w_hm1[((size_t)((g*64 + oc)*64 + ic))*9 + tap];
    else       v = w_attr1[((size_t)(((g-6)*64 + oc)*64 + ic))*9 + tap];
    ws[OFF_WM + i] = (_Float16)v;
    return;
  }
  i -= N_WM;
  if (i < N_W2) {
    // w2[g][tap][oc16][ic64], zero-padded oc
    int ic = i & 63, oc = (i >> 6) & 15, tap = (i >> 10) % 9, g = i / 9216;
    float v = 0.f;
    if (g < 6) { if (oc < 2) v = w_hm2[((size_t)((g*2 + oc)*64 + ic))*9 + tap]; }
    else       { if (oc < 3) v = w_attr2[((size_t)(((g-6)*3 + oc)*64 + ic))*9 + tap]; }
    ws[OFF_W2 + i] = (_Float16)v;
  }
}

// ---------------- shared conv 512->64, MFMA fp16 (swapped: D = W·X), out fp16 NHWC
__global__ __launch_bounds__(256, 4) void shared_conv_mfma(
    const float* __restrict__ x, const int* __restrict__ tmask,
    const _Float16* __restrict__ wsh,
    const float* __restrict__ g_s, const float* __restrict__ b_s,
    const float* __restrict__ m_s, const float* __restrict__ v_s,
    _Float16* __restrict__ shb) {
  int bid = blockIdx.x;
  int b = bid / (TC*TC), t = bid % (TC*TC);
  int ty = t / TC, tx = t % TC;
  int Y0 = ty*10, X0 = tx*10;
  int tid = threadIdx.x;
  _Float16* shp = shb + (size_t)b*HW*HW*64;
  bool active = tmask[b*TC*TC + t] != 0;
  if (!active) {
    for (int i = tid; i < 1600; i += 256) {      // 100 px * 16 q of 4 halfs
      int px = i >> 4, q = i & 15;
      int gy = Y0 + px/10, gx = X0 + px%10;
      *(float2*)(shp + ((size_t)(gy*HW + gx))*64 + q*4) = make_float2(0.f, 0.f);
    }
    return;
  }
  int nact = 0;
  #pragma unroll
  for (int dy = 0; dy < 3; dy++)
    #pragma unroll
    for (int dx = 0; dx < 3; dx++) {
      int tyy = ty+dy-1, txx = tx+dx-1;
      int a = (tyy>=0 && tyy<TC && txx>=0 && txx<TC) ? tmask[b*TC*TC + tyy*TC + txx] : 0;
      nact |= (a != 0) << (dy*3+dx);
    }
  __shared__ _Float16 sm[144*64];   // 18432 B, swizzled rows of 128 B
  int lane = tid & 63, w = tid >> 6;
  int mh = w >> 1, nh = w & 1;
  int l15 = lane & 15, l4 = lane >> 4;
  // per-fi A-row bases (out px -> input row base); px = f*16 + l15
  int r0[4];
  #pragma unroll
  for (int fi = 0; fi < 4; fi++) {
    int f = mh + fi*2;
    int p = f*16 + l15; if (p > 99) p = 99;
    r0[fi] = (p/10)*12 + (p%10);
  }
  f32x4 acc[4][2];
  #pragma unroll
  for (int fi = 0; fi < 4; fi++)
    #pragma unroll
    for (int j = 0; j < 2; j++) acc[fi][j] = (f32x4)0.f;

  for (int ck = 0; ck < 8; ck++) {
    __syncthreads();
    for (int i = tid; i < 1152; i += 256) {     // 144 px * 8 slots
      int px = i % 144, s8 = i / 144;
      int ry = px/12, rx = px%12;
      int gy = Y0-1+ry, gx = X0-1+rx;
      int selr = (ry==0)?0:((ry<=10)?1:2);
      int selc = (rx==0)?0:((rx<=10)?1:2);
      bool ok = (gy>=0 && gy<HW && gx>=0 && gx<HW) && ((nact>>(selr*3+selc))&1);
      half8 hv;
      #pragma unroll
      for (int j = 0; j < 8; j++) hv[j] = (_Float16)0.f;
      if (ok) {
        const float* xp = x + (((size_t)b*512 + ck*64 + s8*8)*HW + gy)*HW + gx;
        #pragma unroll
        for (int j = 0; j < 8; j++) hv[j] = (_Float16)xp[(size_t)j*HW*HW];
      }
      *(half8*)((char*)sm + px*128 + (((s8 ^ (px&7)) & 7)<<4)) = hv;
    }
    __syncthreads();
    for (int tap = 0; tap < 9; tap++) {
      int ky = tap/3, kx = tap%3;
      int radd = ky*12 + kx;
      #pragma unroll
      for (int ks = 0; ks < 2; ks++) {
        half8 bf[2];
        #pragma unroll
        for (int j = 0; j < 2; j++) {
          int oc = (nh*2 + j)*16 + l15;
          bf[j] = *(const half8*)(wsh + (size_t)(tap*64 + oc)*512 + ck*64 + ks*32 + l4*8);
        }
        #pragma unroll
        for (int fi = 0; fi < 4; fi++) {
          int f = mh + fi*2;
          if (f < 7) {
            int r = r0[fi] + radd;
            half8 af = *(const half8*)((const char*)sm + (r<<7) + ((((ks*4 + l4) ^ r) & 7)<<4));
            // swapped: D[oc][px] — lane holds 4 consecutive oc at one px
            acc[fi][0] = __builtin_amdgcn_mfma_f32_16x16x32_f16(bf[0], af, acc[fi][0], 0, 0, 0);
            acc[fi][1] = __builtin_amdgcn_mfma_f32_16x16x32_f16(bf[1], af, acc[fi][1], 0, 0, 0);
          }
        }
      }
    }
  }
  // BN + ReLU -> fp16 NHWC; lane: px = f*16+l15, oc = (nh*2+j)*16 + l4*4 + r
  float sc4[2][4], sh4[2][4];
  #pragma unroll
  for (int j = 0; j < 2; j++) {
    int ocb = (nh*2 + j)*16 + l4*4;
    float4 gg = *(const float4*)&g_s[ocb];
    float4 vv = *(const float4*)&v_s[ocb];
    float4 bb = *(const float4*)&b_s[ocb];
    float4 mm = *(const float4*)&m_s[ocb];
    float gA[4] = {gg.x,gg.y,gg.z,gg.w}, vA[4] = {vv.x,vv.y,vv.z,vv.w};
    float bA[4] = {bb.x,bb.y,bb.z,bb.w}, mA[4] = {mm.x,mm.y,mm.z,mm.w};
    #pragma unroll
    for (int r = 0; r < 4; r++) {
      float s = gA[r] * rsqrtf(vA[r] + EPSF);
      sc4[j][r] = s; sh4[j][r] = bA[r] - mA[r]*s;
    }
  }
  #pragma unroll
  for (int fi = 0; fi < 4; fi++) {
    int f = mh + fi*2;
    if (f < 7) {
      int p = f*16 + l15;
      if (p < 100) {
        int gy = Y0 + p/10, gx = X0 + p%10;
        _Float16* dst = shp + ((size_t)(gy*HW + gx))*64;
        #pragma unroll
        for (int j = 0; j < 2; j++) {
          int ocb = (nh*2 + j)*16 + l4*4;
          half4 hv;
          #pragma unroll
          for (int r = 0; r < 4; r++)
            hv[r] = (_Float16)fmaxf(fmaf(acc[fi][j][r], sc4[j][r], sh4[j][r]), 0.f);
          *(half4*)(dst + ocb) = hv;
        }
      }
    }
  }
}

// -------- branch: block = (tile, group-pair); wave = (M-half) x (one group, 64 oc)
// mid conv 64->64 per group + grouped 64->{2,3}; h1 aliases dead input tile.
__global__ __launch_bounds__(256, 3) void branch_conv_mfma(
    const _Float16* __restrict__ shb, const int* __restrict__ tmask,
    const _Float16* __restrict__ wm, const _Float16* __restrict__ w2,
    const float* __restrict__ g_h, const float* __restrict__ b_h,
    const float* __restrict__ m_h, const float* __restrict__ v_h,
    const float* __restrict__ g_a, const float* __restrict__ b_a,
    const float* __restrict__ m_a, const float* __restrict__ v_a,
    const float* __restrict__ bias_hm, const float* __restrict__ bias_attr,
    float* __restrict__ out) {
  int bid = blockIdx.x;
  int g2 = bid % 18;                 // group pair id: groups g2*2, g2*2+1
  int t = bid / 18;
  int b = t / (TC*TC); t %= (TC*TC);
  int ty = t / TC, tx = t % TC;
  int Y0 = ty*10, X0 = tx*10;
  int tid = threadIdx.x;
  bool active = tmask[b*TC*TC + ty*TC + tx] != 0;
  if (!active) {
    if (tid < 100) {
      int py = tid/10, pxx = tid%10;
      #pragma unroll
      for (int gi = 0; gi < 2; gi++) {
        int g = g2*2 + gi;
        int Oc = (g < 6) ? 2 : 3;
        int cobase = (g < 6) ? g*2 : 12 + (g-6)*3;
        for (int o = 0; o < Oc; o++)
          out[(((size_t)b*102 + cobase + o)*HW + (Y0+py))*HW + (X0+pxx)] = 0.f;
      }
    }
    return;
  }
  int nact = 0;
  #pragma unroll
  for (int dy = 0; dy < 3; dy++)
    #pragma unroll
    for (int dx = 0; dx < 3; dx++) {
      int tyy = ty+dy-1, txx = tx+dx-1;
      int a = (tyy>=0 && tyy<TC && txx>=0 && txx<TC) ? tmask[b*TC*TC + tyy*TC + txx] : 0;
      nact |= (a != 0) << (dy*3+dx);
    }
  // input: rows 0..195 (196*128B); h0: rows 196..339; h1 aliases input rows 0..143
  __shared__ _Float16 sm[(196 + 144)*64];   // 43520 B
  const _Float16* shp = shb + (size_t)b*HW*HW*64;
  int lane = tid & 63, w = tid >> 6;
  int gi = w & 1, m = w >> 1;
  int g = g2*2 + gi;
  int l15 = lane & 15, l4 = lane >> 4;

  // stage 14x14x64 fp16 tile (swizzled)
  for (int i = tid; i < 1568; i += 256) {       // 196 px * 8 slots
    int px = i >> 3, s8 = i & 7;
    int ry = px/14, rx = px%14;
    int gy = Y0-2+ry, gx = X0-2+rx;
    half8 hv;
    if (gy>=0 && gy<HW && gx>=0 && gx<HW)
      hv = *(const half8*)(shp + ((size_t)(gy*HW + gx))*64 + s8*8);
    else {
      #pragma unroll
      for (int j = 0; j < 8; j++) hv[j] = (_Float16)0.f;
    }
    *(half8*)((char*)sm + px*128 + (((s8 ^ px) & 7)<<4)) = hv;
  }
  __syncthreads();

  // mid conv for group gi: Mfrags gf = m*5 + fi (gf<9), N = 64 oc (4 Nfrags)
  int r0[5];
  #pragma unroll
  for (int fi = 0; fi < 5; fi++) {
    int gf = m*5 + fi;
    int p = gf*16 + l15; if (p > 143) p = 143;
    r0[fi] = (p/12)*14 + (p%12);
  }
  f32x4 acc[5][4];
  #pragma unroll
  for (int fi = 0; fi < 5; fi++)
    #pragma unroll
    for (int nf = 0; nf < 4; nf++) acc[fi][nf] = (f32x4)0.f;

  const _Float16* wmg = wm + (size_t)g*9*64*64;
  for (int tap = 0; tap < 9; tap++) {
    int radd = (tap/3)*14 + (tap%3);
    #pragma unroll
    for (int ks = 0; ks < 2; ks++) {
      half8 bf[4];
      #pragma unroll
      for (int nf = 0; nf < 4; nf++)
        bf[nf] = *(const half8*)(wmg + (size_t)(tap*64 + nf*16 + l15)*64 + ks*32 + l4*8);
      #pragma unroll
      for (int fi = 0; fi < 5; fi++) {
        int gf = m*5 + fi;
        if (gf < 9) {
          int r = r0[fi] + radd;
          half8 af = *(const half8*)((const char*)sm + (r<<7) + ((((ks*4 + l4) ^ r) & 7)<<4));
          #pragma unroll
          for (int nf = 0; nf < 4; nf++)
            acc[fi][nf] = __builtin_amdgcn_mfma_f32_16x16x32_f16(bf[nf], af, acc[fi][nf], 0, 0, 0);
        }
      }
    }
  }

  // BN + ReLU + pixel mask -> h (fp16, swizzled rows of 128B)
  // phase 0: gi==0 waves write h0 (separate region); barrier; phase 1: gi==1 -> h1 (aliases input)
  {
    int cbase = (g < 6) ? g*64 : (g-6)*64;
    const float* GG = (g < 6) ? g_h : g_a;
    const float* VV = (g < 6) ? v_h : v_a;
    const float* BB = (g < 6) ? b_h : b_a;
    const float* MM = (g < 6) ? m_h : m_a;
    float sc4[4][4], sh4[4][4];
    #pragma unroll
    for (int nf = 0; nf < 4; nf++) {
      int c = cbase + nf*16 + l4*4;
      float4 gg = *(const float4*)&GG[c];
      float4 vv = *(const float4*)&VV[c];
      float4 bb = *(const float4*)&BB[c];
      float4 mm = *(const float4*)&MM[c];
      float gA[4] = {gg.x,gg.y,gg.z,gg.w}, vA[4] = {vv.x,vv.y,vv.z,vv.w};
      float bA[4] = {bb.x,bb.y,bb.z,bb.w}, mA[4] = {mm.x,mm.y,mm.z,mm.w};
      #pragma unroll
      for (int r = 0; r < 4; r++) {
        float s = gA[r] * rsqrtf(vA[r] + EPSF);
        sc4[nf][r] = s; sh4[nf][r] = bA[r] - mA[r]*s;
      }
    }
    #pragma unroll
    for (int phase = 0; phase < 2; phase++) {
      if (gi == phase) {
        _Float16* hb = (phase == 0) ? (_Float16*)sm + 196*64 : (_Float16*)sm;
        #pragma unroll
        for (int fi = 0; fi < 5; fi++) {
          int gf = m*5 + fi;
          if (gf < 9) {
            int px = gf*16 + l15;                 // 0..143
            int hy = px/12, hx = px - hy*12;
            int selr = (hy==0)?0:((hy<=10)?1:2);
            int selc = (hx==0)?0:((hx<=10)?1:2);
            bool ok = (nact>>(selr*3+selc)) & 1;
            #pragma unroll
            for (int nf = 0; nf < 4; nf++) {
              int ocb = nf*16 + l4*4;
              half4 hv;
              #pragma unroll
              for (int r = 0; r < 4; r++) {
                float v = ok ? fmaxf(fmaf(acc[fi][nf][r], sc4[nf][r], sh4[nf][r]), 0.f) : 0.f;
                hv[r] = (_Float16)v;
              }
              *(half4*)((char*)hb + (px<<7) + ((((ocb>>3) ^ px) & 7)<<4) + (ocb&7)*2) = hv;
            }
          }
        }
      }
      __syncthreads();
    }
  }

  // out conv: wave (m, gi) -> group gi, Mfrags f = m*4 + fi (f<7), N = 16 (Oc used)
  const _Float16* hb = (gi == 0) ? (const _Float16*)sm + 196*64 : (const _Float16*)sm;
  int r0b[4];
  #pragma unroll
  for (int fi = 0; fi < 4; fi++) {
    int f = m*4 + fi;
    int p = f*16 + l15; if (p > 99) p = 99;
    r0b[fi] = (p/10)*12 + (p%10);
  }
  f32x4 acc2[4];
  #pragma unroll
  for (int fi = 0; fi < 4; fi++) acc2[fi] = (f32x4)0.f;
  const _Float16* w2g = w2 + (size_t)g*9*16*64;
  for (int tap = 0; tap < 9; tap++) {
    int radd = (tap/3)*12 + (tap%3);
    #pragma unroll
    for (int ks = 0; ks < 2; ks++) {
      half8 bf = *(const half8*)(w2g + (size_t)(tap*16 + l15)*64 + ks*32 + l4*8);
      #pragma unroll
      for (int fi = 0; fi < 4; fi++) {
        int f = m*4 + fi;
        if (f < 7) {
          int r = r0b[fi] + radd;
          half8 af = *(const half8*)((const char*)hb + (r<<7) + ((((ks*4 + l4) ^ r) & 7)<<4));
          acc2[fi] = __builtin_amdgcn_mfma_f32_16x16x32_f16(bf, af, acc2[fi], 0, 0, 0);
        }
      }
    }
  }
  // store: lane l4==0 holds oc = reg (0..3), px = f*16 + l15 (row-coalesced)
  int Oc = (g < 6) ? 2 : 3;
  int cobase = (g < 6) ? g*2 : 12 + (g-6)*3;
  float bo[3];
  #pragma unroll
  for (int o = 0; o < 3; o++)
    bo[o] = (o < Oc) ? ((g < 6) ? bias_hm[g*2 + o] : bias_attr[(g-6)*3 + o]) : 0.f;
  #pragma unroll
  for (int fi = 0; fi < 4; fi++) {
    int f = m*4 + fi;
    int p = f*16 + l15;
    if (f < 7 && l4 == 0 && p < 100) {
      int gy = Y0 + p/10, gx = X0 + p%10;
      float* op = out + (((size_t)b*102 + cobase)*HW + gy)*HW + gx;
      #pragma unroll
      for (int o = 0; o < 3; o++)
        if (o < Oc) op[(size_t)o*HW*HW] = acc2[fi][o] + bo[o];
    }
  }
}

extern "C" void kernel_launch(void* const* d_in, const int* in_sizes, int n_in,
                              void* d_out, int out_size, void* d_ws, size_t ws_size,
                              hipStream_t stream) {
  const float* x        = (const float*)d_in[0];
  const int*   tmask    = (const int*)  d_in[1];
  const float* w_s      = (const float*)d_in[2];
  const float* g_s      = (const float*)d_in[3];
  const float* b_s      = (const float*)d_in[4];
  const float* m_s      = (const float*)d_in[5];
  const float* v_s      = (const float*)d_in[6];
  const float* w_hm1    = (const float*)d_in[7];
  const float* g_h      = (const float*)d_in[8];
  const float* b_h      = (const float*)d_in[9];
  const float* m_h      = (const float*)d_in[10];
  const float* v_h      = (const float*)d_in[11];
  const float* w_hm2    = (const float*)d_in[12];
  const float* bias_hm  = (const float*)d_in[13];
  const float* w_attr1  = (const float*)d_in[14];
  const float* g_a      = (const float*)d_in[15];
  const float* b_a      = (const float*)d_in[16];
  const float* m_a      = (const float*)d_in[17];
  const float* v_a      = (const float*)d_in[18];
  const float* w_attr2  = (const float*)d_in[19];
  const float* bias_attr= (const float*)d_in[20];
  _Float16* ws = (_Float16*)d_ws;
  float* out = (float*)d_out;

  int prep_total = N_WSH + N_WM + N_W2;
  prep_kernel<<<(prep_total + 255)/256, 256, 0, stream>>>(
      w_s, w_hm1, w_attr1, w_hm2, w_attr2, ws);
  shared_conv_mfma<<<2*TC*TC, 256, 0, stream>>>(
      x, tmask, ws + OFF_WSH, g_s, b_s, m_s, v_s, ws + OFF_SHB);
  branch_conv_mfma<<<2*TC*TC*18, 256, 0, stream>>>(
      ws + OFF_SHB, tmask, ws + OFF_WM, ws + OFF_W2,
      g_h, b_h, m_h, v_h, g_a, b_a, m_a, v_a, bias_hm, bias_attr, out);
}